// Round 1
// baseline (468.076 us; speedup 1.0000x reference)
//
#include <hip/hip_runtime.h>
#include <math.h>

typedef unsigned int uint;
typedef unsigned short ushort;
typedef short short8 __attribute__((ext_vector_type(8)));
typedef float f32x4 __attribute__((ext_vector_type(4)));

#define B_ 2048
#define N_ 256
#define D_ 64
#define ND_ 16384
#define NN_ 65536
#define KIDX_ 52428u

// ---------------- ws layout (bytes) ----------------
#define WS_NODE   ((size_t)0)                    // node/final bf16 [B][N*D] : 64 MiB
#define WS_W1T    ((size_t)64*1024*1024)         // W1^T bf16 [n][e][k] : 2 MiB
#define WS_W2T    (WS_W1T + (size_t)2*1024*1024) // 2 MiB
#define WS_GPT    (WS_W2T + (size_t)2*1024*1024) // gpW1^T bf16 [e][k=16384] : 2 MiB
#define WS_ADJF   (WS_GPT + (size_t)2*1024*1024) // adj packed A-frag bf16 : 128 KiB
#define WS_GPARTS (WS_ADJF + (size_t)256*1024)   // split-K partials f32 [8][2048][64] : 4 MiB
#define WS_HIST   (WS_GPARTS + (size_t)4*1024*1024)
#define WS_HIST2  (WS_HIST + (size_t)65536*4)
#define WS_SCAL   (WS_HIST2 + (size_t)65536*4)

__device__ __forceinline__ ushort f2bf(float f) {
    uint u = __float_as_uint(f);
    u += 0x7fffu + ((u >> 16) & 1u);
    return (ushort)(u >> 16);
}
__device__ __forceinline__ float bf2f(ushort u) { return __uint_as_float(((uint)u) << 16); }

// ---------------- weight convert/transpose ----------------
// blocks 0..255: W1[n][k][e] -> W1t[n][e][k] bf16
// blocks 256..511: W2
// blocks 512..767: gpW1[k][e] (tile of 64 k) -> gpW1t[e][k] bf16
__global__ __launch_bounds__(256) void k_convert(const float* __restrict__ W1,
                                                 const float* __restrict__ W2,
                                                 const float* __restrict__ gpW1,
                                                 ushort* __restrict__ W1t,
                                                 ushort* __restrict__ W2t,
                                                 ushort* __restrict__ gpt) {
    __shared__ ushort T[64][66];
    int bid = blockIdx.x, tid = threadIdx.x;
    const float* src;
    if (bid < 256) src = W1 + (size_t)bid * 4096;
    else if (bid < 512) src = W2 + (size_t)(bid - 256) * 4096;
    else src = gpW1 + (size_t)(bid - 512) * 64 * 64;
#pragma unroll
    for (int i = 0; i < 16; i++) {
        int idx = i * 256 + tid;
        int k = idx >> 6, e = idx & 63;
        T[e][k] = f2bf(src[idx]);
    }
    __syncthreads();
#pragma unroll
    for (int i = 0; i < 16; i++) {
        int idx = i * 256 + tid;
        int e = idx >> 6, k = idx & 63;
        ushort v = T[e][k];
        if (bid < 256) W1t[(size_t)bid * 4096 + idx] = v;
        else if (bid < 512) W2t[(size_t)(bid - 256) * 4096 + idx] = v;
        else gpt[(size_t)e * 16384 + (size_t)(bid - 512) * 64 + k] = v;
    }
}

// ---------------- sigmoid + top16 histogram ----------------
__global__ __launch_bounds__(256) void k_sig_hist(const float* __restrict__ adj_param,
                                                  float* __restrict__ sig,
                                                  uint* __restrict__ hist) {
    int i = blockIdx.x * 256 + threadIdx.x;
    float a = adj_param[i];
    // f32 pipeline with correctly-rounded exp (mimic numpy float32 path)
    float t = (float)exp(-(double)a);
    float s = 1.0f / (1.0f + t);
    sig[i] = s;
    atomicAdd(&hist[__float_as_uint(s) >> 16], 1u);
}

// ---------------- exact radix select (one pass over a 65536-bin hist) ----------------
// pass==0: rank = KIDX; writes scal[0]=bucket (top16), scal[1]=count_below
// pass==1: rank = KIDX - scal[1]; writes scal[4] = float bits of threshold
__global__ __launch_bounds__(256) void k_select(const uint* __restrict__ hist,
                                                uint* __restrict__ scal, int pass) {
    __shared__ uint psum[256];
    int t = threadIdx.x;
    uint s = 0;
    for (int j = 0; j < 256; j++) s += hist[t * 256 + j];
    psum[t] = s;
    __syncthreads();
    if (t == 0) {
        uint rank = KIDX_ - (pass ? scal[1] : 0u);
        uint c = 0; uint k = 0;
        for (k = 0; k < 256; k++) { uint p = psum[k]; if (c + p > rank) break; c += p; }
        uint bucket = 0;
        for (uint j = 0; j < 256; j++) {
            uint h = hist[k * 256 + j];
            if (c + h > rank) { bucket = k * 256 + j; break; }
            c += h;
        }
        if (!pass) { scal[0] = bucket; scal[1] = c; }
        else       { scal[4] = (scal[0] << 16) | bucket; }
    }
}

__global__ __launch_bounds__(256) void k_hist2(const float* __restrict__ sig,
                                               const uint* __restrict__ scal,
                                               uint* __restrict__ hist2) {
    int i = blockIdx.x * 256 + threadIdx.x;
    uint bits = __float_as_uint(sig[i]);
    if ((bits >> 16) == scal[0]) atomicAdd(&hist2[bits & 0xffffu], 1u);
}

// ---------------- threshold + zero-diag; write adj fp32 out + A-frag-packed bf16 ----------------
__global__ __launch_bounds__(256) void k_thresh(float* __restrict__ sig,
                                                const uint* __restrict__ scal,
                                                ushort* __restrict__ adjF) {
    int i = blockIdx.x * 256 + threadIdx.x;
    float thr = __uint_as_float(scal[4]);
    float s = sig[i];
    int r = i >> 8, c = i & 255;
    float v = (s > thr && r != c) ? s : 0.0f;
    sig[i] = v;
    // A-fragment pack: A[m=r][k=c], chunk=(((r>>4)*8 + (c>>5))*4 + ((c>>3)&3))*16 + (r&15), pos=c&7
    uint chunk = ((((uint)(r >> 4) * 8u + (uint)(c >> 5)) * 4u + (uint)((c >> 3) & 3)) * 16u + (uint)(r & 15));
    adjF[chunk * 8u + (uint)(c & 7)] = f2bf(v);
}

// ---------------- stage 1: per-node 2-layer MLP (grouped GEMM, bf16 MFMA) ----------------
// grid (32 btiles, 256 nodes), 256 thr. A-frags from global x; B from LDS (pre-transposed W).
__global__ __launch_bounds__(256) void k_node(const float* __restrict__ x,
                                              const ushort* __restrict__ W1t,
                                              const ushort* __restrict__ W2t,
                                              const float* __restrict__ b1,
                                              const float* __restrict__ b2,
                                              ushort* __restrict__ node) {
    __shared__ ushort Ws1[64][72];
    __shared__ ushort Ws2[64][72];
    __shared__ ushort Hs[64][72];
    int tid = threadIdx.x;
    int bt = blockIdx.x, n = blockIdx.y;
    int b0 = bt * 64;
#pragma unroll
    for (int i = 0; i < 16; i++) {
        int idx = i * 256 + tid;
        int e = idx >> 6, k = idx & 63;
        Ws1[e][k] = W1t[(size_t)n * 4096 + idx];
        Ws2[e][k] = W2t[(size_t)n * 4096 + idx];
    }
    __syncthreads();

    int wid = tid >> 6, lane = tid & 63, quad = lane >> 4, l16 = lane & 15;
    const float* xrow = x + (size_t)(b0 + wid * 16 + l16) * ND_ + n * 64;

    short8 afrag[2];
#pragma unroll
    for (int ks = 0; ks < 2; ks++) {
        const float* p = xrow + ks * 32 + quad * 8;
        float4 q0 = *(const float4*)p;
        float4 q1 = *(const float4*)(p + 4);
        short8 a;
        a[0] = (short)f2bf(q0.x); a[1] = (short)f2bf(q0.y);
        a[2] = (short)f2bf(q0.z); a[3] = (short)f2bf(q0.w);
        a[4] = (short)f2bf(q1.x); a[5] = (short)f2bf(q1.y);
        a[6] = (short)f2bf(q1.z); a[7] = (short)f2bf(q1.w);
        afrag[ks] = a;
    }
    f32x4 acc[4];
#pragma unroll
    for (int nt = 0; nt < 4; nt++) acc[nt] = (f32x4){0.f, 0.f, 0.f, 0.f};
#pragma unroll
    for (int ks = 0; ks < 2; ks++) {
#pragma unroll
        for (int nt = 0; nt < 4; nt++) {
            short8 bf = *(const short8*)&Ws1[nt * 16 + l16][ks * 32 + quad * 8];
            acc[nt] = __builtin_amdgcn_mfma_f32_16x16x32_bf16(afrag[ks], bf, acc[nt], 0, 0, 0);
        }
    }
    const float* b1p = b1 + n * 64;
#pragma unroll
    for (int nt = 0; nt < 4; nt++) {
        float bias = b1p[nt * 16 + l16];
#pragma unroll
        for (int r = 0; r < 4; r++) {
            float h = fmaxf(acc[nt][r] + bias, 0.0f);
            Hs[wid * 16 + quad * 4 + r][nt * 16 + l16] = f2bf(h);
        }
    }
    __syncthreads();

    f32x4 acc2[4];
#pragma unroll
    for (int nt = 0; nt < 4; nt++) acc2[nt] = (f32x4){0.f, 0.f, 0.f, 0.f};
#pragma unroll
    for (int ks = 0; ks < 2; ks++) {
        short8 a2 = *(const short8*)&Hs[wid * 16 + l16][ks * 32 + quad * 8];
#pragma unroll
        for (int nt = 0; nt < 4; nt++) {
            short8 bf = *(const short8*)&Ws2[nt * 16 + l16][ks * 32 + quad * 8];
            acc2[nt] = __builtin_amdgcn_mfma_f32_16x16x32_bf16(a2, bf, acc2[nt], 0, 0, 0);
        }
    }
    const float* b2p = b2 + n * 64;
#pragma unroll
    for (int nt = 0; nt < 4; nt++) {
        float bias = b2p[nt * 16 + l16];
#pragma unroll
        for (int r = 0; r < 4; r++) {
            float v = acc2[nt][r] + bias;
            node[(size_t)(b0 + wid * 16 + quad * 4 + r) * ND_ + n * 64 + nt * 16 + l16] = f2bf(v);
        }
    }
}

// ---------------- stage 2: mixing GEMM per batch + residual; final overwrites node[b] ----------------
// C[i][d] = sum_j adj[i][j]*node[b][j][d]; final = 0.5C + 0.5node
__global__ __launch_bounds__(256) void k_mix(const ushort* __restrict__ adjF,
                                             ushort* __restrict__ node) {
    __shared__ ushort Bs[32 * 64 * 8]; // chunk (jc,d): ((jc*64+d)*8 + jj)
    int b = blockIdx.x, tid = threadIdx.x;
    int wid = tid >> 6, L = tid & 63, quad = L >> 4, l16 = L & 15;
    ushort* nb = node + (size_t)b * ND_;

    // staging: global -> regs -> shfl 8x8 ushort transpose -> frag-packed LDS
#pragma unroll
    for (int t = 0; t < 8; t++) {
        int jc = wid + t * 4;
        const ushort* src = nb + (jc * 8 + (L & 7)) * 64 + (L >> 3) * 8;
        uint4 dw = *(const uint4*)src;
        int srcBase = (L >> 3) * 8;
        int sel = (L & 7) >> 1;
        int hi = L & 1;
        uint outw[4];
#pragma unroll
        for (int jp = 0; jp < 4; jp++) {
            uint lo16, hi16;
            {
                int sl = srcBase + 2 * jp;
                uint t0 = (uint)__shfl((int)dw.x, sl, 64);
                uint t1 = (uint)__shfl((int)dw.y, sl, 64);
                uint t2 = (uint)__shfl((int)dw.z, sl, 64);
                uint t3 = (uint)__shfl((int)dw.w, sl, 64);
                uint tv = sel == 0 ? t0 : sel == 1 ? t1 : sel == 2 ? t2 : t3;
                lo16 = hi ? (tv >> 16) : (tv & 0xffffu);
            }
            {
                int sl = srcBase + 2 * jp + 1;
                uint t0 = (uint)__shfl((int)dw.x, sl, 64);
                uint t1 = (uint)__shfl((int)dw.y, sl, 64);
                uint t2 = (uint)__shfl((int)dw.z, sl, 64);
                uint t3 = (uint)__shfl((int)dw.w, sl, 64);
                uint tv = sel == 0 ? t0 : sel == 1 ? t1 : sel == 2 ? t2 : t3;
                hi16 = hi ? (tv >> 16) : (tv & 0xffffu);
            }
            outw[jp] = lo16 | (hi16 << 16);
        }
        uint4 o; o.x = outw[0]; o.y = outw[1]; o.z = outw[2]; o.w = outw[3];
        *(uint4*)&Bs[(jc * 64 + L) * 8] = o;
    }
    __syncthreads();

    f32x4 acc[4][4];
#pragma unroll
    for (int mt = 0; mt < 4; mt++)
#pragma unroll
        for (int nt = 0; nt < 4; nt++) acc[mt][nt] = (f32x4){0.f, 0.f, 0.f, 0.f};

    for (int ks = 0; ks < 8; ks++) {
        short8 af[4];
#pragma unroll
        for (int mt = 0; mt < 4; mt++) {
            int it = wid * 4 + mt;
            af[mt] = *(const short8*)&adjF[(size_t)((((it * 8 + ks) * 4 + quad) * 16 + l16)) * 8];
        }
        short8 bfr[4];
#pragma unroll
        for (int nt = 0; nt < 4; nt++) {
            bfr[nt] = *(const short8*)&Bs[((ks * 4 + quad) * 64 + nt * 16 + l16) * 8];
        }
#pragma unroll
        for (int mt = 0; mt < 4; mt++)
#pragma unroll
            for (int nt = 0; nt < 4; nt++)
                acc[mt][nt] = __builtin_amdgcn_mfma_f32_16x16x32_bf16(af[mt], bfr[nt], acc[mt][nt], 0, 0, 0);
    }

#pragma unroll
    for (int mt = 0; mt < 4; mt++) {
        int itbase = (wid * 4 + mt) * 16;
#pragma unroll
        for (int nt = 0; nt < 4; nt++) {
            int d = nt * 16 + l16;
#pragma unroll
            for (int r = 0; r < 4; r++) {
                int i = itbase + quad * 4 + r;
                float nodev = bf2f(Bs[((i >> 3) * 64 + d) * 8 + (i & 7)]);
                float v = 0.5f * acc[mt][nt][r] + 0.5f * nodev;
                nb[i * 64 + d] = f2bf(v);
            }
        }
    }
}

// ---------------- stage 3: global pool GEMM [2048 x 16384] @ [16384 x 64], split-K=8 ----------------
__global__ __launch_bounds__(256) void k_gp1(const ushort* __restrict__ finalb,
                                             const ushort* __restrict__ gpt,
                                             float* __restrict__ gparts) {
    int bt = blockIdx.x, ksp = blockIdx.y, tid = threadIdx.x;
    int wid = tid >> 6, lane = tid & 63, quad = lane >> 4, l16 = lane & 15;
    size_t kc = (size_t)ksp * 2048;
    int brow = bt * 64 + wid * 16 + l16;
    const ushort* arow = finalb + (size_t)brow * ND_ + kc;
    f32x4 acc[4];
#pragma unroll
    for (int nt = 0; nt < 4; nt++) acc[nt] = (f32x4){0.f, 0.f, 0.f, 0.f};
    for (int ks = 0; ks < 64; ks++) {
        short8 af = *(const short8*)(arow + ks * 32 + quad * 8);
#pragma unroll
        for (int nt = 0; nt < 4; nt++) {
            short8 bf = *(const short8*)(gpt + (size_t)(nt * 16 + l16) * ND_ + kc + ks * 32 + quad * 8);
            acc[nt] = __builtin_amdgcn_mfma_f32_16x16x32_bf16(af, bf, acc[nt], 0, 0, 0);
        }
    }
    float* gp = gparts + ((size_t)ksp * B_ + bt * 64) * 64;
#pragma unroll
    for (int nt = 0; nt < 4; nt++)
#pragma unroll
        for (int r = 0; r < 4; r++) {
            int b_loc = wid * 16 + quad * 4 + r;
            int e = nt * 16 + l16;
            gp[b_loc * 64 + e] = acc[nt][r];
        }
}

// ---------------- stage 4: reduce partials, bias+relu, gp2 (all fp32) ----------------
__global__ __launch_bounds__(64) void k_gp2(const float* __restrict__ gparts,
                                            const float* __restrict__ gpb1,
                                            const float* __restrict__ gpW2,
                                            const float* __restrict__ gpb2,
                                            float* __restrict__ out) {
    __shared__ float gs[64];
    int b = blockIdx.x, e = threadIdx.x;
    float s = gpb1[e];
#pragma unroll
    for (int p = 0; p < 8; p++) s += gparts[((size_t)p * B_ + b) * 64 + e];
    gs[e] = fmaxf(s, 0.0f);
    __syncthreads();
    if (e < 32) {
        float a = gpb2[e];
        for (int k2 = 0; k2 < 64; k2++) a += gs[k2] * gpW2[k2 * 32 + e];
        out[(size_t)b * 32 + e] = a;
    }
}

extern "C" void kernel_launch(void* const* d_in, const int* in_sizes, int n_in,
                              void* d_out, int out_size, void* d_ws, size_t ws_size,
                              hipStream_t stream) {
    const float* x = (const float*)d_in[0];
    const float* adj_param = (const float*)d_in[1];
    const float* W1 = (const float*)d_in[2];
    const float* b1 = (const float*)d_in[3];
    const float* W2 = (const float*)d_in[4];
    const float* b2 = (const float*)d_in[5];
    const float* gpW1 = (const float*)d_in[6];
    const float* gpb1 = (const float*)d_in[7];
    const float* gpW2 = (const float*)d_in[8];
    const float* gpb2 = (const float*)d_in[9];

    float* out = (float*)d_out;                 // [2048*32]
    float* adj_out = (float*)d_out + NN_;       // [256*256]

    char* ws = (char*)d_ws;
    ushort* node = (ushort*)(ws + WS_NODE);
    ushort* W1t = (ushort*)(ws + WS_W1T);
    ushort* W2t = (ushort*)(ws + WS_W2T);
    ushort* gpt = (ushort*)(ws + WS_GPT);
    ushort* adjF = (ushort*)(ws + WS_ADJF);
    float* gparts = (float*)(ws + WS_GPARTS);
    uint* hist1 = (uint*)(ws + WS_HIST);
    uint* hist2 = (uint*)(ws + WS_HIST2);
    uint* scal = (uint*)(ws + WS_SCAL);

    hipMemsetAsync(ws + WS_HIST, 0, 2 * 65536 * 4 + 64, stream);

    k_convert<<<768, 256, 0, stream>>>(W1, W2, gpW1, W1t, W2t, gpt);
    k_sig_hist<<<256, 256, 0, stream>>>(adj_param, adj_out, hist1);
    k_select<<<1, 256, 0, stream>>>(hist1, scal, 0);
    k_hist2<<<256, 256, 0, stream>>>(adj_out, scal, hist2);
    k_select<<<1, 256, 0, stream>>>(hist2, scal, 1);
    k_thresh<<<256, 256, 0, stream>>>(adj_out, scal, adjF);
    k_node<<<dim3(32, 256), 256, 0, stream>>>(x, W1t, W2t, b1, b2, node);
    k_mix<<<2048, 256, 0, stream>>>(adjF, node);
    k_gp1<<<dim3(32, 8), 256, 0, stream>>>(node, gpt, gparts);
    k_gp2<<<2048, 64, 0, stream>>>(gparts, gpb1, gpW2, gpb2, out);
}

// Round 2
// 457.447 us; speedup vs baseline: 1.0232x; 1.0232x over previous
//
#include <hip/hip_runtime.h>
#include <math.h>

typedef unsigned int uint;
typedef unsigned short ushort;
typedef short short8 __attribute__((ext_vector_type(8)));
typedef float f32x4 __attribute__((ext_vector_type(4)));

#define B_ 2048
#define N_ 256
#define D_ 64
#define ND_ 16384
#define NN_ 65536
#define KIDX_ 52428u

// ---------------- ws layout (bytes) ----------------
#define WS_NODE   ((size_t)0)                    // node/final bf16 [B][N*D] : 64 MiB
#define WS_W1T    ((size_t)64*1024*1024)         // W1^T bf16 [n][e][k] : 2 MiB
#define WS_W2T    (WS_W1T + (size_t)2*1024*1024) // 2 MiB
#define WS_GPT    (WS_W2T + (size_t)2*1024*1024) // gpW1^T bf16 [e][k=16384] : 2 MiB
#define WS_ADJF   (WS_GPT + (size_t)2*1024*1024) // adj packed A-frag bf16 : 128 KiB
#define WS_GPARTS (WS_ADJF + (size_t)256*1024)   // split-K partials f32 [8][2048][64] : 4 MiB
#define WS_SCAL   (WS_GPARTS + (size_t)4*1024*1024 + 512*1024)

__device__ __forceinline__ ushort f2bf(float f) {
    uint u = __float_as_uint(f);
    u += 0x7fffu + ((u >> 16) & 1u);
    return (ushort)(u >> 16);
}
__device__ __forceinline__ float bf2f(ushort u) { return __uint_as_float(((uint)u) << 16); }

// exact float sigmoid via correctly-rounded double exp (matches numpy f32 pipeline; verified R1)
__device__ __forceinline__ float sigmoid_exact(float a) {
    float t = (float)exp(-(double)a);
    return 1.0f / (1.0f + t);
}

// ---------------- weight convert/transpose ----------------
__global__ __launch_bounds__(256) void k_convert(const float* __restrict__ W1,
                                                 const float* __restrict__ W2,
                                                 const float* __restrict__ gpW1,
                                                 ushort* __restrict__ W1t,
                                                 ushort* __restrict__ W2t,
                                                 ushort* __restrict__ gpt) {
    __shared__ ushort T[64][66];
    int bid = blockIdx.x, tid = threadIdx.x;
    const float* src;
    if (bid < 256) src = W1 + (size_t)bid * 4096;
    else if (bid < 512) src = W2 + (size_t)(bid - 256) * 4096;
    else src = gpW1 + (size_t)(bid - 512) * 64 * 64;
#pragma unroll
    for (int i = 0; i < 16; i++) {
        int idx = i * 256 + tid;
        int k = idx >> 6, e = idx & 63;
        T[e][k] = f2bf(src[idx]);
    }
    __syncthreads();
#pragma unroll
    for (int i = 0; i < 16; i++) {
        int idx = i * 256 + tid;
        int e = idx >> 6, k = idx & 63;
        ushort v = T[e][k];
        if (bid < 256) W1t[(size_t)bid * 4096 + idx] = v;
        else if (bid < 512) W2t[(size_t)(bid - 256) * 4096 + idx] = v;
        else gpt[(size_t)e * 16384 + (size_t)(bid - 512) * 64 + k] = v;
    }
}

// ---------------- exact rank select in PARAM space (monotone sigmoid ⇒ same rank) --------
// Single workgroup, 4 passes of 8-bit radix over signed-order keys, LDS hists only.
// Writes scal[0] = float bits of sigmoid(param_at_rank) — the threshold.
__global__ __launch_bounds__(1024) void k_radix_select(const float* __restrict__ adj_param,
                                                       uint* __restrict__ scal) {
    __shared__ uint hist[16][256];
    __shared__ uint red[256];
    __shared__ uint bc[2];
    int tid = threadIdx.x;
    int wv = tid >> 6;
    uint prefix = 0;
    uint rank = KIDX_;
#pragma unroll
    for (int pass = 0; pass < 4; pass++) {
        int shift = 24 - 8 * pass;
        for (int i = tid; i < 16 * 256; i += 1024) ((uint*)hist)[i] = 0u;
        __syncthreads();
        for (int i = 0; i < 64; i++) {
            int idx = i * 1024 + tid;
            uint bits = __float_as_uint(adj_param[idx]);
            uint key = bits ^ ((bits & 0x80000000u) ? 0xFFFFFFFFu : 0x80000000u);
            bool cand;
            if (pass == 0) cand = true;
            else cand = ((key >> (32 - 8 * pass)) == prefix);
            if (cand) atomicAdd(&hist[wv][(key >> shift) & 0xffu], 1u);
        }
        __syncthreads();
        if (tid < 256) {
            uint s = 0;
#pragma unroll
            for (int w = 0; w < 16; w++) s += hist[w][tid];
            red[tid] = s;
        }
        __syncthreads();
        if (tid == 0) {
            uint c = 0;
            for (int b = 0; b < 256; b++) {
                uint h = red[b];
                if (c + h > rank) { bc[0] = (prefix << 8) | (uint)b; bc[1] = rank - c; break; }
                c += h;
            }
        }
        __syncthreads();
        prefix = bc[0];
        rank = bc[1];
        __syncthreads();
    }
    if (tid == 0) {
        uint key = prefix;
        uint bits = (key & 0x80000000u) ? (key ^ 0x80000000u) : ~key;
        float at = __uint_as_float(bits);
        scal[0] = __float_as_uint(sigmoid_exact(at));
    }
}

// ---------------- sigmoid + threshold + zero-diag; write adj fp32 + A-frag bf16 ---------
__global__ __launch_bounds__(256) void k_thresh(const float* __restrict__ adj_param,
                                                const uint* __restrict__ scal,
                                                float* __restrict__ adj_out,
                                                ushort* __restrict__ adjF) {
    int i = blockIdx.x * 256 + threadIdx.x;
    float thr = __uint_as_float(scal[0]);
    float s = sigmoid_exact(adj_param[i]);
    int r = i >> 8, c = i & 255;
    float v = (s > thr && r != c) ? s : 0.0f;
    adj_out[i] = v;
    uint chunk = ((((uint)(r >> 4) * 8u + (uint)(c >> 5)) * 4u + (uint)((c >> 3) & 3)) * 16u + (uint)(r & 15));
    adjF[chunk * 8u + (uint)(c & 7)] = f2bf(v);
}

// ---------------- stage 1: per-node 2-layer MLP ----------------
// grid (8 btiles, 256 nodes): each block does 256 batch rows, weights loaded ONCE.
__global__ __launch_bounds__(256) void k_node(const float* __restrict__ x,
                                              const ushort* __restrict__ W1t,
                                              const ushort* __restrict__ W2t,
                                              const float* __restrict__ b1,
                                              const float* __restrict__ b2,
                                              ushort* __restrict__ node) {
    __shared__ ushort Ws1[64][72];
    __shared__ ushort Ws2[64][72];
    __shared__ ushort Hs[4][16][72];
    int tid = threadIdx.x;
    int bt = blockIdx.x, n = blockIdx.y;
#pragma unroll
    for (int i = 0; i < 16; i++) {
        int idx = i * 256 + tid;
        int e = idx >> 6, k = idx & 63;
        Ws1[e][k] = W1t[(size_t)n * 4096 + idx];
        Ws2[e][k] = W2t[(size_t)n * 4096 + idx];
    }
    __syncthreads();

    int wid = tid >> 6, lane = tid & 63, quad = lane >> 4, l16 = lane & 15;
    const float* b1p = b1 + n * 64;
    const float* b2p = b2 + n * 64;

#pragma unroll
    for (int mt = 0; mt < 4; mt++) {
        int brow = blockIdx.x * 256 + wid * 64 + mt * 16;
        const float* xrow = x + (size_t)(brow + l16) * ND_ + n * 64;

        short8 afrag[2];
#pragma unroll
        for (int ks = 0; ks < 2; ks++) {
            const float* p = xrow + ks * 32 + quad * 8;
            float4 q0 = *(const float4*)p;
            float4 q1 = *(const float4*)(p + 4);
            short8 a;
            a[0] = (short)f2bf(q0.x); a[1] = (short)f2bf(q0.y);
            a[2] = (short)f2bf(q0.z); a[3] = (short)f2bf(q0.w);
            a[4] = (short)f2bf(q1.x); a[5] = (short)f2bf(q1.y);
            a[6] = (short)f2bf(q1.z); a[7] = (short)f2bf(q1.w);
            afrag[ks] = a;
        }
        f32x4 acc[4];
#pragma unroll
        for (int nt = 0; nt < 4; nt++) acc[nt] = (f32x4){0.f, 0.f, 0.f, 0.f};
#pragma unroll
        for (int ks = 0; ks < 2; ks++) {
#pragma unroll
            for (int nt = 0; nt < 4; nt++) {
                short8 bf = *(const short8*)&Ws1[nt * 16 + l16][ks * 32 + quad * 8];
                acc[nt] = __builtin_amdgcn_mfma_f32_16x16x32_bf16(afrag[ks], bf, acc[nt], 0, 0, 0);
            }
        }
#pragma unroll
        for (int nt = 0; nt < 4; nt++) {
            float bias = b1p[nt * 16 + l16];
#pragma unroll
            for (int r = 0; r < 4; r++) {
                float h = fmaxf(acc[nt][r] + bias, 0.0f);
                Hs[wid][quad * 4 + r][nt * 16 + l16] = f2bf(h);
            }
        }
        // per-wave LDS buffer: lockstep write->read, compiler inserts lgkmcnt
        f32x4 acc2[4];
#pragma unroll
        for (int nt = 0; nt < 4; nt++) acc2[nt] = (f32x4){0.f, 0.f, 0.f, 0.f};
#pragma unroll
        for (int ks = 0; ks < 2; ks++) {
            short8 a2 = *(const short8*)&Hs[wid][l16][ks * 32 + quad * 8];
#pragma unroll
            for (int nt = 0; nt < 4; nt++) {
                short8 bf = *(const short8*)&Ws2[nt * 16 + l16][ks * 32 + quad * 8];
                acc2[nt] = __builtin_amdgcn_mfma_f32_16x16x32_bf16(a2, bf, acc2[nt], 0, 0, 0);
            }
        }
#pragma unroll
        for (int nt = 0; nt < 4; nt++) {
            float bias = b2p[nt * 16 + l16];
#pragma unroll
            for (int r = 0; r < 4; r++) {
                float v = acc2[nt][r] + bias;
                node[(size_t)(brow + quad * 4 + r) * ND_ + n * 64 + nt * 16 + l16] = f2bf(v);
            }
        }
    }
}

// ---------------- stage 2: mixing GEMM per batch + residual ----------------
__global__ __launch_bounds__(256) void k_mix(const ushort* __restrict__ adjF,
                                             ushort* __restrict__ node) {
    __shared__ ushort Bs[32 * 64 * 8]; // chunk (jc,d): ((jc*64+d)*8 + jj)
    int b = blockIdx.x, tid = threadIdx.x;
    int wid = tid >> 6, L = tid & 63, quad = L >> 4, l16 = L & 15;
    ushort* nb = node + (size_t)b * ND_;

#pragma unroll
    for (int t = 0; t < 8; t++) {
        int jc = wid + t * 4;
        const ushort* src = nb + (jc * 8 + (L & 7)) * 64 + (L >> 3) * 8;
        uint4 dw = *(const uint4*)src;
        int srcBase = (L >> 3) * 8;
        int sel = (L & 7) >> 1;
        int hi = L & 1;
        uint outw[4];
#pragma unroll
        for (int jp = 0; jp < 4; jp++) {
            uint lo16, hi16;
            {
                int sl = srcBase + 2 * jp;
                uint t0 = (uint)__shfl((int)dw.x, sl, 64);
                uint t1 = (uint)__shfl((int)dw.y, sl, 64);
                uint t2 = (uint)__shfl((int)dw.z, sl, 64);
                uint t3 = (uint)__shfl((int)dw.w, sl, 64);
                uint tv = sel == 0 ? t0 : sel == 1 ? t1 : sel == 2 ? t2 : t3;
                lo16 = hi ? (tv >> 16) : (tv & 0xffffu);
            }
            {
                int sl = srcBase + 2 * jp + 1;
                uint t0 = (uint)__shfl((int)dw.x, sl, 64);
                uint t1 = (uint)__shfl((int)dw.y, sl, 64);
                uint t2 = (uint)__shfl((int)dw.z, sl, 64);
                uint t3 = (uint)__shfl((int)dw.w, sl, 64);
                uint tv = sel == 0 ? t0 : sel == 1 ? t1 : sel == 2 ? t2 : t3;
                hi16 = hi ? (tv >> 16) : (tv & 0xffffu);
            }
            outw[jp] = lo16 | (hi16 << 16);
        }
        uint4 o; o.x = outw[0]; o.y = outw[1]; o.z = outw[2]; o.w = outw[3];
        *(uint4*)&Bs[(jc * 64 + L) * 8] = o;
    }
    __syncthreads();

    f32x4 acc[4][4];
#pragma unroll
    for (int mt = 0; mt < 4; mt++)
#pragma unroll
        for (int nt = 0; nt < 4; nt++) acc[mt][nt] = (f32x4){0.f, 0.f, 0.f, 0.f};

    for (int ks = 0; ks < 8; ks++) {
        short8 af[4];
#pragma unroll
        for (int mt = 0; mt < 4; mt++) {
            int it = wid * 4 + mt;
            af[mt] = *(const short8*)&adjF[(size_t)((((it * 8 + ks) * 4 + quad) * 16 + l16)) * 8];
        }
        short8 bfr[4];
#pragma unroll
        for (int nt = 0; nt < 4; nt++) {
            bfr[nt] = *(const short8*)&Bs[((ks * 4 + quad) * 64 + nt * 16 + l16) * 8];
        }
#pragma unroll
        for (int mt = 0; mt < 4; mt++)
#pragma unroll
            for (int nt = 0; nt < 4; nt++)
                acc[mt][nt] = __builtin_amdgcn_mfma_f32_16x16x32_bf16(af[mt], bfr[nt], acc[mt][nt], 0, 0, 0);
    }

#pragma unroll
    for (int mt = 0; mt < 4; mt++) {
        int itbase = (wid * 4 + mt) * 16;
#pragma unroll
        for (int nt = 0; nt < 4; nt++) {
            int d = nt * 16 + l16;
#pragma unroll
            for (int r = 0; r < 4; r++) {
                int i = itbase + quad * 4 + r;
                float nodev = bf2f(Bs[((i >> 3) * 64 + d) * 8 + (i & 7)]);
                float v = 0.5f * acc[mt][nt][r] + 0.5f * nodev;
                nb[i * 64 + d] = f2bf(v);
            }
        }
    }
}

// ---------------- stage 3: global pool GEMM split-K=8 ----------------
__global__ __launch_bounds__(256) void k_gp1(const ushort* __restrict__ finalb,
                                             const ushort* __restrict__ gpt,
                                             float* __restrict__ gparts) {
    int bt = blockIdx.x, ksp = blockIdx.y, tid = threadIdx.x;
    int wid = tid >> 6, lane = tid & 63, quad = lane >> 4, l16 = lane & 15;
    size_t kc = (size_t)ksp * 2048;
    int brow = bt * 64 + wid * 16 + l16;
    const ushort* arow = finalb + (size_t)brow * ND_ + kc;
    f32x4 acc[4];
#pragma unroll
    for (int nt = 0; nt < 4; nt++) acc[nt] = (f32x4){0.f, 0.f, 0.f, 0.f};
    for (int ks = 0; ks < 64; ks++) {
        short8 af = *(const short8*)(arow + ks * 32 + quad * 8);
#pragma unroll
        for (int nt = 0; nt < 4; nt++) {
            short8 bf = *(const short8*)(gpt + (size_t)(nt * 16 + l16) * ND_ + kc + ks * 32 + quad * 8);
            acc[nt] = __builtin_amdgcn_mfma_f32_16x16x32_bf16(af, bf, acc[nt], 0, 0, 0);
        }
    }
    float* gp = gparts + ((size_t)ksp * B_ + bt * 64) * 64;
#pragma unroll
    for (int nt = 0; nt < 4; nt++)
#pragma unroll
        for (int r = 0; r < 4; r++) {
            int b_loc = wid * 16 + quad * 4 + r;
            int e = nt * 16 + l16;
            gp[b_loc * 64 + e] = acc[nt][r];
        }
}

// ---------------- stage 4: reduce partials, bias+relu, gp2 (fp32) ----------------
__global__ __launch_bounds__(64) void k_gp2(const float* __restrict__ gparts,
                                            const float* __restrict__ gpb1,
                                            const float* __restrict__ gpW2,
                                            const float* __restrict__ gpb2,
                                            float* __restrict__ out) {
    __shared__ float gs[64];
    int b = blockIdx.x, e = threadIdx.x;
    float s = gpb1[e];
#pragma unroll
    for (int p = 0; p < 8; p++) s += gparts[((size_t)p * B_ + b) * 64 + e];
    gs[e] = fmaxf(s, 0.0f);
    __syncthreads();
    if (e < 32) {
        float a = gpb2[e];
        for (int k2 = 0; k2 < 64; k2++) a += gs[k2] * gpW2[k2 * 32 + e];
        out[(size_t)b * 32 + e] = a;
    }
}

extern "C" void kernel_launch(void* const* d_in, const int* in_sizes, int n_in,
                              void* d_out, int out_size, void* d_ws, size_t ws_size,
                              hipStream_t stream) {
    const float* x = (const float*)d_in[0];
    const float* adj_param = (const float*)d_in[1];
    const float* W1 = (const float*)d_in[2];
    const float* b1 = (const float*)d_in[3];
    const float* W2 = (const float*)d_in[4];
    const float* b2 = (const float*)d_in[5];
    const float* gpW1 = (const float*)d_in[6];
    const float* gpb1 = (const float*)d_in[7];
    const float* gpW2 = (const float*)d_in[8];
    const float* gpb2 = (const float*)d_in[9];

    float* out = (float*)d_out;                 // [2048*32]
    float* adj_out = (float*)d_out + NN_;       // [256*256]

    char* ws = (char*)d_ws;
    ushort* node = (ushort*)(ws + WS_NODE);
    ushort* W1t = (ushort*)(ws + WS_W1T);
    ushort* W2t = (ushort*)(ws + WS_W2T);
    ushort* gpt = (ushort*)(ws + WS_GPT);
    ushort* adjF = (ushort*)(ws + WS_ADJF);
    float* gparts = (float*)(ws + WS_GPARTS);
    uint* scal = (uint*)(ws + WS_SCAL);

    k_convert<<<768, 256, 0, stream>>>(W1, W2, gpW1, W1t, W2t, gpt);
    k_radix_select<<<1, 1024, 0, stream>>>(adj_param, scal);
    k_thresh<<<256, 256, 0, stream>>>(adj_param, scal, adj_out, adjF);
    k_node<<<dim3(8, 256), 256, 0, stream>>>(x, W1t, W2t, b1, b2, node);
    k_mix<<<2048, 256, 0, stream>>>(adjF, node);
    k_gp1<<<dim3(32, 8), 256, 0, stream>>>(node, gpt, gparts);
    k_gp2<<<2048, 64, 0, stream>>>(gparts, gpb1, gpW2, gpb2, out);
}

// Round 3
// 383.290 us; speedup vs baseline: 1.2212x; 1.1935x over previous
//
#include <hip/hip_runtime.h>
#include <math.h>

typedef unsigned int uint;
typedef unsigned short ushort;
typedef short short8 __attribute__((ext_vector_type(8)));
typedef float f32x4 __attribute__((ext_vector_type(4)));

#define B_ 2048
#define N_ 256
#define D_ 64
#define ND_ 16384
#define NN_ 65536
#define KIDX_ 52428u
#define SPLITK 16

// ---------------- ws layout (bytes) ----------------
// gparts overlays W1t/W2t (+4 MB beyond) — dead by the time k_gp1 runs.
#define WS_NODE   ((size_t)0)                      // node/final bf16 [B][N*D] : 64 MiB
#define WS_GPT    ((size_t)64*1024*1024)           // gpW1^T bf16 [e][k] : 2 MiB
#define WS_ADJF   (WS_GPT + (size_t)2*1024*1024)   // adj A-frag bf16 : 256 KiB slot
#define WS_W1T    (WS_ADJF + (size_t)256*1024)     // 2 MiB (dead after k_node)
#define WS_W2T    (WS_W1T + (size_t)2*1024*1024)   // 2 MiB (dead after k_node)
#define WS_GPARTS (WS_W1T)                         // overlay: f32 [16][2048][64] = 8 MiB
#define WS_SCAL   (WS_GPARTS + (size_t)8*1024*1024)

__device__ __forceinline__ ushort f2bf(float f) {
    uint u = __float_as_uint(f);
    u += 0x7fffu + ((u >> 16) & 1u);
    return (ushort)(u >> 16);
}
__device__ __forceinline__ float bf2f(ushort u) { return __uint_as_float(((uint)u) << 16); }

// exact float sigmoid via correctly-rounded double exp (matches numpy; verified R1/R2)
__device__ __forceinline__ float sigmoid_exact(float a) {
    float t = (float)exp(-(double)a);
    return 1.0f / (1.0f + t);
}

// ---------------- weight convert/transpose ----------------
__global__ __launch_bounds__(256) void k_convert(const float* __restrict__ W1,
                                                 const float* __restrict__ W2,
                                                 const float* __restrict__ gpW1,
                                                 ushort* __restrict__ W1t,
                                                 ushort* __restrict__ W2t,
                                                 ushort* __restrict__ gpt) {
    __shared__ ushort T[64][66];
    int bid = blockIdx.x, tid = threadIdx.x;
    const float* src;
    if (bid < 256) src = W1 + (size_t)bid * 4096;
    else if (bid < 512) src = W2 + (size_t)(bid - 256) * 4096;
    else src = gpW1 + (size_t)(bid - 512) * 64 * 64;
#pragma unroll
    for (int i = 0; i < 16; i++) {
        int idx = i * 256 + tid;
        int k = idx >> 6, e = idx & 63;
        T[e][k] = f2bf(src[idx]);
    }
    __syncthreads();
#pragma unroll
    for (int i = 0; i < 16; i++) {
        int idx = i * 256 + tid;
        int e = idx >> 6, k = idx & 63;
        ushort v = T[e][k];
        if (bid < 256) W1t[(size_t)bid * 4096 + idx] = v;
        else if (bid < 512) W2t[(size_t)(bid - 256) * 4096 + idx] = v;
        else gpt[(size_t)e * 16384 + (size_t)(bid - 512) * 64 + k] = v;
    }
}

// ---------------- exact rank select in PARAM space ----------------
// Per-LANE histogram columns histL[bin][64]: no same-address contention, 2 lanes/bank (free).
__global__ __launch_bounds__(1024, 4) void k_radix_select(const float* __restrict__ adj_param,
                                                          uint* __restrict__ scal) {
    __shared__ uint histL[256 * 64];   // [bin][lane] : 64 KiB
    __shared__ uint red[256];
    __shared__ uint bc[2];
    int tid = threadIdx.x;
    int lane = tid & 63;
    uint prefix = 0;
    uint rank = KIDX_;
    const uint4* pv = (const uint4*)adj_param;
#pragma unroll 1
    for (int pass = 0; pass < 4; pass++) {
        int shift = 24 - 8 * pass;
        for (int i = tid; i < 256 * 64; i += 1024) histL[i] = 0u;
        __syncthreads();
#pragma unroll 1
        for (int i = 0; i < 16; i++) {
            uint4 b4 = pv[i * 1024 + tid];
#pragma unroll
            for (int c = 0; c < 4; c++) {
                uint bits = (c == 0) ? b4.x : (c == 1) ? b4.y : (c == 2) ? b4.z : b4.w;
                uint key = bits ^ ((bits & 0x80000000u) ? 0xFFFFFFFFu : 0x80000000u);
                bool cand = (pass == 0) || ((key >> (32 - 8 * pass)) == prefix);
                if (cand) atomicAdd(&histL[(((key >> shift) & 0xffu) << 6) + lane], 1u);
            }
        }
        __syncthreads();
        if (tid < 256) {
            uint s = 0;
#pragma unroll
            for (int l = 0; l < 64; l++) s += histL[(tid << 6) + ((l + tid) & 63)];
            red[tid] = s;
        }
        __syncthreads();
        if (tid == 0) {
            uint c = 0;
            for (int b = 0; b < 256; b++) {
                uint h = red[b];
                if (c + h > rank) { bc[0] = (prefix << 8) | (uint)b; bc[1] = rank - c; break; }
                c += h;
            }
        }
        __syncthreads();
        prefix = bc[0];
        rank = bc[1];
        __syncthreads();
    }
    if (tid == 0) {
        uint key = prefix;
        uint bits = (key & 0x80000000u) ? (key ^ 0x80000000u) : ~key;
        scal[0] = __float_as_uint(sigmoid_exact(__uint_as_float(bits)));
    }
}

// ---------------- sigmoid + threshold + zero-diag; write adj fp32 + A-frag bf16 ---------
__global__ __launch_bounds__(256) void k_thresh(const float* __restrict__ adj_param,
                                                const uint* __restrict__ scal,
                                                float* __restrict__ adj_out,
                                                ushort* __restrict__ adjF) {
    int i = blockIdx.x * 256 + threadIdx.x;
    float thr = __uint_as_float(scal[0]);
    float s = sigmoid_exact(adj_param[i]);
    int r = i >> 8, c = i & 255;
    float v = (s > thr && r != c) ? s : 0.0f;
    adj_out[i] = v;
    uint chunk = ((((uint)(r >> 4) * 8u + (uint)(c >> 5)) * 4u + (uint)((c >> 3) & 3)) * 16u + (uint)(r & 15));
    adjF[chunk * 8u + (uint)(c & 7)] = f2bf(v);
}

// ---------------- stage 1: per-node 2-layer MLP ----------------
// grid (256 n FASTEST, 8 bt): concurrent blocks stream a contiguous 16 MB x-window.
// All 16 x-loads issued up front (ILP latency hiding).
__global__ __launch_bounds__(256) void k_node(const float* __restrict__ x,
                                              const ushort* __restrict__ W1t,
                                              const ushort* __restrict__ W2t,
                                              const float* __restrict__ b1,
                                              const float* __restrict__ b2,
                                              ushort* __restrict__ node) {
    __shared__ ushort Ws1[64][72];
    __shared__ ushort Ws2[64][72];
    __shared__ ushort Hs[4][16][72];
    int tid = threadIdx.x;
    int n = blockIdx.x, bt = blockIdx.y;

    const uint4* w1v = (const uint4*)(W1t + (size_t)n * 4096);
    const uint4* w2v = (const uint4*)(W2t + (size_t)n * 4096);
#pragma unroll
    for (int i = 0; i < 2; i++) {
        int idx = i * 256 + tid;          // 0..511 uint4
        int e = idx >> 3, k0 = (idx & 7) * 8;
        *(uint4*)&Ws1[e][k0] = w1v[idx];
        *(uint4*)&Ws2[e][k0] = w2v[idx];
    }
    __syncthreads();

    int wid = tid >> 6, lane = tid & 63, quad = lane >> 4, l16 = lane & 15;
    const float* b1p = b1 + n * 64;
    const float* b2p = b2 + n * 64;
    int brow0 = bt * 256 + wid * 64;

    // prefetch + convert ALL x fragments (16 float4 loads in flight)
    short8 fa[4][2];
#pragma unroll
    for (int mt = 0; mt < 4; mt++) {
        const float* xr = x + (size_t)(brow0 + mt * 16 + l16) * ND_ + n * 64;
#pragma unroll
        for (int ks = 0; ks < 2; ks++) {
            const float* p = xr + ks * 32 + quad * 8;
            float4 q0 = *(const float4*)p;
            float4 q1 = *(const float4*)(p + 4);
            short8 a;
            a[0] = (short)f2bf(q0.x); a[1] = (short)f2bf(q0.y);
            a[2] = (short)f2bf(q0.z); a[3] = (short)f2bf(q0.w);
            a[4] = (short)f2bf(q1.x); a[5] = (short)f2bf(q1.y);
            a[6] = (short)f2bf(q1.z); a[7] = (short)f2bf(q1.w);
            fa[mt][ks] = a;
        }
    }

#pragma unroll
    for (int mt = 0; mt < 4; mt++) {
        int brow = brow0 + mt * 16;
        f32x4 acc[4];
#pragma unroll
        for (int nt = 0; nt < 4; nt++) acc[nt] = (f32x4){0.f, 0.f, 0.f, 0.f};
#pragma unroll
        for (int ks = 0; ks < 2; ks++) {
#pragma unroll
            for (int nt = 0; nt < 4; nt++) {
                short8 bf = *(const short8*)&Ws1[nt * 16 + l16][ks * 32 + quad * 8];
                acc[nt] = __builtin_amdgcn_mfma_f32_16x16x32_bf16(fa[mt][ks], bf, acc[nt], 0, 0, 0);
            }
        }
#pragma unroll
        for (int nt = 0; nt < 4; nt++) {
            float bias = b1p[nt * 16 + l16];
#pragma unroll
            for (int r = 0; r < 4; r++) {
                float h = fmaxf(acc[nt][r] + bias, 0.0f);
                Hs[wid][quad * 4 + r][nt * 16 + l16] = f2bf(h);
            }
        }
        // per-wave LDS buffer; DS ops in-order per wave => no barrier needed
        f32x4 acc2[4];
#pragma unroll
        for (int nt = 0; nt < 4; nt++) acc2[nt] = (f32x4){0.f, 0.f, 0.f, 0.f};
#pragma unroll
        for (int ks = 0; ks < 2; ks++) {
            short8 a2 = *(const short8*)&Hs[wid][l16][ks * 32 + quad * 8];
#pragma unroll
            for (int nt = 0; nt < 4; nt++) {
                short8 bf = *(const short8*)&Ws2[nt * 16 + l16][ks * 32 + quad * 8];
                acc2[nt] = __builtin_amdgcn_mfma_f32_16x16x32_bf16(a2, bf, acc2[nt], 0, 0, 0);
            }
        }
#pragma unroll
        for (int nt = 0; nt < 4; nt++) {
            float bias = b2p[nt * 16 + l16];
#pragma unroll
            for (int r = 0; r < 4; r++) {
                float v = acc2[nt][r] + bias;
                node[(size_t)(brow + quad * 4 + r) * ND_ + n * 64 + nt * 16 + l16] = f2bf(v);
            }
        }
    }
}

// ---------------- stage 2: mixing GEMM per batch + residual ----------------
// LDS transposed staging Bt[d][j] with XOR-octet swizzle o=(j>>3)^(d&7):
// b16 scatter writes and b128 frag reads both ~2-way max.
__global__ __launch_bounds__(256) void k_mix(const ushort* __restrict__ adjF,
                                             ushort* __restrict__ node) {
    __shared__ ushort Bt[64 * 264];   // row stride 264 ushorts (528B = 132 banks ≡ 4 mod 32)
    int b = blockIdx.x, tid = threadIdx.x;
    int wid = tid >> 6, L = tid & 63, quad = L >> 4, l16 = L & 15;
    ushort* nb = node + (size_t)b * ND_;

    // staging: coalesced b128 read (8 j-rows x 128B per wave-instr), transposed b16 writes
#pragma unroll
    for (int t = 0; t < 8; t++) {
        int j = t * 32 + (tid >> 3);
        int d0 = (tid & 7) * 8;
        uint4 dw = *(const uint4*)(nb + j * 64 + d0);
        int jo = j >> 3, jl = j & 7;
        ushort vals[8];
        vals[0] = (ushort)(dw.x & 0xffffu); vals[1] = (ushort)(dw.x >> 16);
        vals[2] = (ushort)(dw.y & 0xffffu); vals[3] = (ushort)(dw.y >> 16);
        vals[4] = (ushort)(dw.z & 0xffffu); vals[5] = (ushort)(dw.z >> 16);
        vals[6] = (ushort)(dw.w & 0xffffu); vals[7] = (ushort)(dw.w >> 16);
#pragma unroll
        for (int c = 0; c < 8; c++) {
            // element (j, d0+c) at Bt[(d0+c)*264 + ((jo ^ c) * 8) + jl]  (d0%8==0 => (d&7)==c)
            Bt[(d0 + c) * 264 + ((jo ^ c) << 3) + jl] = vals[c];
        }
    }
    __syncthreads();

    f32x4 acc[4][4];
#pragma unroll
    for (int mt = 0; mt < 4; mt++)
#pragma unroll
        for (int nt = 0; nt < 4; nt++) acc[mt][nt] = (f32x4){0.f, 0.f, 0.f, 0.f};

#pragma unroll 2
    for (int ks = 0; ks < 8; ks++) {
        short8 af[4];
#pragma unroll
        for (int mt = 0; mt < 4; mt++) {
            int it = wid * 4 + mt;
            af[mt] = *(const short8*)&adjF[(size_t)((((it * 8 + ks) * 4 + quad) * 16 + l16)) * 8];
        }
        short8 bfr[4];
#pragma unroll
        for (int nt = 0; nt < 4; nt++) {
            int d = nt * 16 + l16;
            int o = (ks * 4 + quad) ^ (d & 7);
            bfr[nt] = *(const short8*)&Bt[d * 264 + (o << 3)];
        }
#pragma unroll
        for (int mt = 0; mt < 4; mt++)
#pragma unroll
            for (int nt = 0; nt < 4; nt++)
                acc[mt][nt] = __builtin_amdgcn_mfma_f32_16x16x32_bf16(af[mt], bfr[nt], acc[mt][nt], 0, 0, 0);
    }

#pragma unroll
    for (int mt = 0; mt < 4; mt++) {
        int itbase = (wid * 4 + mt) * 16;
#pragma unroll
        for (int nt = 0; nt < 4; nt++) {
            int d = nt * 16 + l16;
#pragma unroll
            for (int r = 0; r < 4; r++) {
                int i = itbase + quad * 4 + r;
                int o = (i >> 3) ^ (d & 7);
                float nodev = bf2f(Bt[d * 264 + (o << 3) + (i & 7)]);
                float v = 0.5f * acc[mt][nt][r] + 0.5f * nodev;
                nb[i * 64 + d] = f2bf(v);
            }
        }
    }
}

// ---------------- stage 3: global pool GEMM split-K=16 (512 blocks, 8 waves/CU) --------
__global__ __launch_bounds__(256) void k_gp1(const ushort* __restrict__ finalb,
                                             const ushort* __restrict__ gpt,
                                             float* __restrict__ gparts) {
    int bt = blockIdx.x, ksp = blockIdx.y, tid = threadIdx.x;
    int wid = tid >> 6, lane = tid & 63, quad = lane >> 4, l16 = lane & 15;
    size_t kc = (size_t)ksp * (16384 / SPLITK);
    int brow = bt * 64 + wid * 16 + l16;
    const ushort* arow = finalb + (size_t)brow * ND_ + kc;
    f32x4 acc[4];
#pragma unroll
    for (int nt = 0; nt < 4; nt++) acc[nt] = (f32x4){0.f, 0.f, 0.f, 0.f};
#pragma unroll 4
    for (int ks = 0; ks < (16384 / SPLITK) / 32; ks++) {
        short8 af = *(const short8*)(arow + ks * 32 + quad * 8);
#pragma unroll
        for (int nt = 0; nt < 4; nt++) {
            short8 bf = *(const short8*)(gpt + (size_t)(nt * 16 + l16) * ND_ + kc + ks * 32 + quad * 8);
            acc[nt] = __builtin_amdgcn_mfma_f32_16x16x32_bf16(af, bf, acc[nt], 0, 0, 0);
        }
    }
    float* gp = gparts + ((size_t)ksp * B_ + bt * 64) * 64;
#pragma unroll
    for (int nt = 0; nt < 4; nt++)
#pragma unroll
        for (int r = 0; r < 4; r++) {
            int b_loc = wid * 16 + quad * 4 + r;
            int e = nt * 16 + l16;
            gp[b_loc * 64 + e] = acc[nt][r];
        }
}

// ---------------- stage 4: reduce partials, bias+relu, gp2 (fp32) ----------------
__global__ __launch_bounds__(64) void k_gp2(const float* __restrict__ gparts,
                                            const float* __restrict__ gpb1,
                                            const float* __restrict__ gpW2,
                                            const float* __restrict__ gpb2,
                                            float* __restrict__ out) {
    __shared__ float gs[64];
    int b = blockIdx.x, e = threadIdx.x;
    float s = gpb1[e];
#pragma unroll
    for (int p = 0; p < SPLITK; p++) s += gparts[((size_t)p * B_ + b) * 64 + e];
    gs[e] = fmaxf(s, 0.0f);
    __syncthreads();
    if (e < 32) {
        float a = gpb2[e];
#pragma unroll 8
        for (int k2 = 0; k2 < 64; k2++) a += gs[k2] * gpW2[k2 * 32 + e];
        out[(size_t)b * 32 + e] = a;
    }
}

extern "C" void kernel_launch(void* const* d_in, const int* in_sizes, int n_in,
                              void* d_out, int out_size, void* d_ws, size_t ws_size,
                              hipStream_t stream) {
    const float* x = (const float*)d_in[0];
    const float* adj_param = (const float*)d_in[1];
    const float* W1 = (const float*)d_in[2];
    const float* b1 = (const float*)d_in[3];
    const float* W2 = (const float*)d_in[4];
    const float* b2 = (const float*)d_in[5];
    const float* gpW1 = (const float*)d_in[6];
    const float* gpb1 = (const float*)d_in[7];
    const float* gpW2 = (const float*)d_in[8];
    const float* gpb2 = (const float*)d_in[9];

    float* out = (float*)d_out;                 // [2048*32]
    float* adj_out = (float*)d_out + NN_;       // [256*256]

    char* ws = (char*)d_ws;
    ushort* node = (ushort*)(ws + WS_NODE);
    ushort* gpt = (ushort*)(ws + WS_GPT);
    ushort* adjF = (ushort*)(ws + WS_ADJF);
    ushort* W1t = (ushort*)(ws + WS_W1T);
    ushort* W2t = (ushort*)(ws + WS_W2T);
    float* gparts = (float*)(ws + WS_GPARTS);   // overlays W1t/W2t (dead after k_node)
    uint* scal = (uint*)(ws + WS_SCAL);

    k_convert<<<768, 256, 0, stream>>>(W1, W2, gpW1, W1t, W2t, gpt);
    k_radix_select<<<1, 1024, 0, stream>>>(adj_param, scal);
    k_thresh<<<256, 256, 0, stream>>>(adj_param, scal, adj_out, adjF);
    k_node<<<dim3(256, 8), 256, 0, stream>>>(x, W1t, W2t, b1, b2, node);
    k_mix<<<2048, 256, 0, stream>>>(adjF, node);
    k_gp1<<<dim3(32, SPLITK), 256, 0, stream>>>(node, gpt, gparts);
    k_gp2<<<2048, 64, 0, stream>>>(gparts, gpb1, gpW2, gpb2, out);
}